// Round 16
// baseline (28.756 us; speedup 1.0000x reference)
//
#include <hip/hip_runtime.h>

#define NOUT 10
#define SIG_DIM 584   // 8 + 64 + 512
#define TS 36         // X^T word stride: (36c+t)%32=(4c+t)%32 -> b128 conflict-free

__device__ __forceinline__ float rdlane(float x, int lane) {
    return __int_as_float(__builtin_amdgcn_readlane(__float_as_int(x), lane));
}
__device__ __forceinline__ float comp4(float4 v, int c) {
    return c == 0 ? v.x : c == 1 ? v.y : c == 2 ? v.z : v.w;
}

// PARALLEL-IN-TIME (r12 structure, r13 regrouped math -- both refcheck'd):
//   cp_t = X[t]-X[0]; dx_t = X[t+1]-X[t]
//   gg_t = dx_j*(cp_i + 0.5*dx_i)  (= dS2);  hh_t = dx_j*(dx_i/6 + 0.5*cp_i)
//   w_t  = hh_t + (gg-hh)_{t-1};   S2f = sum gg
//   A[k] = sum_t w_t*X[t][k] + (gg-hh)_last*X[t0+32][k]
//   S3[ijk] = S2f[ij]*X127[k] - A[ijk];  S1 = X127-X0  (exact telescopes)
// Block = 1 batch, 4 waves = 4 independent 32-step chunks, additive combine.
// Per step: 8 rdlane (rows from staged regs) + 8 FMA + ~9 scalar = 25 VALU;
// only X[t] rows needed (not X[t+1]) -> no xcr/xnr arrays (r12's VGPR hog).
// __launch_bounds__(256,8) pins VGPR<=64 -> 8 waves/SIMD (2x r12's TLP).
// Rolled g-loop: ds_read latency hidden by sibling waves, not unrolling.
__global__ __launch_bounds__(256, 8) void sig_linear_kernel(
    const float* __restrict__ X, const float* __restrict__ W,
    const float* __restrict__ bias, float* __restrict__ out)
{
    __shared__ __align__(16) float s_xT[4][8 * TS];  // per-wave X^T, 33 rows used
    __shared__ float s_s2[4][64];
    __shared__ float s_part[4][16];

    const int tid = threadIdx.x;
    const int w = tid >> 6, l = tid & 63, i = l >> 3, j = l & 7;
    const int b = blockIdx.x;
    const int t0 = w * 32;
    const float* Xb = X + (size_t)b * 1024;

    // Stage (r12-proven): lane l holds X row t0+(l>>1), cols cb..cb+3 in d4
    // (readlane source: chunk-row s -> lane 2s cols 0-3, lane 2s+1 cols 4-7);
    // also transposed into LDS. Row t0+32 staged by lanes 0,1 (clamped to 127
    // for w=3: then dx_127=0 -> boundary term exactly 0).
    const int rl_ = l >> 1, cb = (l & 1) * 4;
    const float4 d4 = *reinterpret_cast<const float4*>(Xb + (t0 + rl_) * 8 + cb);
    float* xT = &s_xT[w][0];
    xT[(cb + 0) * TS + rl_] = d4.x;
    xT[(cb + 1) * TS + rl_] = d4.y;
    xT[(cb + 2) * TS + rl_] = d4.z;
    xT[(cb + 3) * TS + rl_] = d4.w;
    if (l < 2) {
        const int rN = (t0 + 32 < 128) ? t0 + 32 : 127;
        const float4 e4 = *reinterpret_cast<const float4*>(Xb + rN * 8 + l * 4);
        xT[(l * 4 + 0) * TS + 32] = e4.x;
        xT[(l * 4 + 1) * TS + 32] = e4.y;
        xT[(l * 4 + 2) * TS + 32] = e4.z;
        xT[(l * 4 + 3) * TS + 32] = e4.w;
    }
    const float x0i = Xb[i];
    const float x0j = Xb[j];
    __syncthreads();

    float A[8];
#pragma unroll
    for (int k = 0; k < 8; ++k) A[k] = 0.f;
    float S2f = 0.f, gp = 0.f;          // gp = (gg-hh)_{t-1}

    const float* icol = xT + i * TS;
    const float* jcol = xT + j * TS;

    float4 ic = *reinterpret_cast<const float4*>(icol);
    float4 jc = *reinterpret_cast<const float4*>(jcol);

#pragma unroll 1
    for (int g = 0; g < 8; ++g) {
        float4 in4, jn4;
        if (g < 7) {
            in4 = *reinterpret_cast<const float4*>(icol + 4 * g + 4);
            jn4 = *reinterpret_cast<const float4*>(jcol + 4 * g + 4);
        } else {
            in4 = make_float4(icol[32], 0.f, 0.f, 0.f);
            jn4 = make_float4(jcol[32], 0.f, 0.f, 0.f);
        }
#pragma unroll
        for (int q = 0; q < 4; ++q) {
            const float xci = comp4(ic, q);
            const float xcj = comp4(jc, q);
            const float xni = (q < 3) ? comp4(ic, q + 1) : in4.x;
            const float xnj = (q < 3) ? comp4(jc, q + 1) : jn4.x;
            const float dxi = xni - xci;
            const float dxj = xnj - xcj;
            const float cpi = xci - x0i;
            const float gg = dxj * fmaf(0.5f, dxi, cpi);          // dS2[ij]
            const float hh = dxj * fmaf(1.0f / 6.0f, dxi, 0.5f * cpi);
            const float wt = hh + gp;
            gp = gg - hh;
            S2f += gg;
            const int lb = 8 * g + 2 * q;   // wave-uniform readlane base
#pragma unroll
            for (int k = 0; k < 8; ++k) {
                const float rk = rdlane(comp4(d4, k & 3), lb + (k >> 2));
                A[k] = fmaf(wt, rk, A[k]);
            }
        }
        ic = in4;
        jc = jn4;
    }
    {   // boundary: A += gp_end * X[t0+32][k] (uniform LDS broadcasts)
#pragma unroll
        for (int k = 0; k < 8; ++k) A[k] = fmaf(gp, xT[k * TS + 32], A[k]);
    }

    // Additive combine of S2f across chunks (exact).
    s_s2[w][l] = S2f;
    __syncthreads();
    const float S2T = s_s2[0][l] + s_s2[1][l] + s_s2[2][l] + s_s2[3][l];

    // Epilogue (r12-verified): out[o] = sum_l [S2T*(W3.X127+W2) - W3.A] + W1.S1 + bias
    const float s1jv = Xb[1016 + j] - x0j;
    const float4 x7a = *reinterpret_cast<const float4*>(Xb + 1016);
    const float4 x7b = *reinterpret_cast<const float4*>(Xb + 1020);
#pragma unroll 1
    for (int o = 0; o < NOUT; ++o) {
        const float* wrow = W + o * SIG_DIM;
        const float4 w0 = *reinterpret_cast<const float4*>(wrow + 72 + l * 8);
        const float4 w1 = *reinterpret_cast<const float4*>(wrow + 72 + l * 8 + 4);
        float dA = w0.x * A[0];
        dA = fmaf(w0.y, A[1], dA); dA = fmaf(w0.z, A[2], dA);
        dA = fmaf(w0.w, A[3], dA); dA = fmaf(w1.x, A[4], dA);
        dA = fmaf(w1.y, A[5], dA); dA = fmaf(w1.z, A[6], dA);
        dA = fmaf(w1.w, A[7], dA);
        float part = -dA;
        if (w == 0) {
            float e = w0.x * x7a.x;
            e = fmaf(w0.y, x7a.y, e); e = fmaf(w0.z, x7a.z, e);
            e = fmaf(w0.w, x7a.w, e); e = fmaf(w1.x, x7b.x, e);
            e = fmaf(w1.y, x7b.y, e); e = fmaf(w1.z, x7b.z, e);
            e = fmaf(w1.w, x7b.w, e);
            part = fmaf(S2T, e + wrow[8 + l], part);
            if (i == 0) part = fmaf(s1jv, wrow[j], part);   // S1 contribution
        }
#pragma unroll
        for (int off = 32; off > 0; off >>= 1) part += __shfl_xor(part, off);
        if (l == o) s_part[w][o] = part;
    }
    __syncthreads();
    if (tid < NOUT)
        out[b * NOUT + tid] = s_part[0][tid] + s_part[1][tid] +
                              s_part[2][tid] + s_part[3][tid] + bias[tid];
}

extern "C" void kernel_launch(void* const* d_in, const int* in_sizes, int n_in,
                              void* d_out, int out_size, void* d_ws, size_t ws_size,
                              hipStream_t stream) {
    const float* X = (const float*)d_in[0];     // (2048, 128, 8)
    const float* W = (const float*)d_in[1];     // (10, 584)
    const float* bias = (const float*)d_in[2];  // (10,)
    float* out = (float*)d_out;                 // (2048, 10)
    sig_linear_kernel<<<dim3(2048), dim3(256), 0, stream>>>(X, W, bias, out);
}